// Round 15
// baseline (80.780 us; speedup 1.0000x reference)
//
#include <hip/hip_runtime.h>
#include <math.h>

// ChamferDistance: B=4, N=M=8192, 3-D fp32 points.
// out[0] = mean_i sqrt(min_j d2)*w  +  mean_j sqrt(min_i d2)
//
// MFMA formulation (R6+): d2 = qsq + (rsq - 2 q.r) as a K=5 dot on
// v_mfma_f32_32x32x16_f16 (32 refs x 32 queries = 1024 pairs/inst):
//   A (refs)    = (-2rx,-2ry,-2rz, rsq_hi, rsq_lo, 0,0,0) f16, lanes 0-31
//   B (queries) = (  qx,  qy,  qz,   1,      1,    0,0,0) f16, lanes 0-31
// lanes 32-63 (k=8..15) zero. D: col=lane&31=query; 16 regs x lane-half =
// 32 refs -> per-lane min3 fold + one shfl_xor(32). absmax 0.0 verified.
//
// R15: ZERO-LDS structure. R9-R14 falsified every scheduling theory; the
// invariant across all was the LDS-stage -> barrier -> ds_read K-loop.
// Serial pipe sum per CU: MFMA 7.2us (8.45 cyc/MFMA is per-CU, not
// per-SIMD) + DS 5.1 + fold 3.4 + staging ~2 ~= measured ~22 if overlap
// is poor (lockstep between barriers). Fix: hold the 8 A-fragments of a
// 256-ref chunk IN REGISTERS (32 VGPRs), loaded straight from a prepped
// global fragment array — no LDS, no __syncthreads, no ds_read. K-loop
// is pure MFMA + fold. Prep kernel rebuilds (-2x,-2y,-2z,rsq_hi,rsq_lo)
// A-frags, (x,y,z,1,1) B-frags, and fp32 qsq per cloud.

#define EPS 1e-8f

typedef _Float16 f16x8 __attribute__((ext_vector_type(8)));
typedef float    f32x16 __attribute__((ext_vector_type(16)));

constexpr int B_    = 4;
constexpr int N_    = 8192;          // points per batch (N == M)
constexpr int TPB   = 256;           // 4 waves
constexpr int QPW   = 64;            // queries per wave (2 tiles of 32)
constexpr int QPB   = 4 * QPW;       // 256 queries per block
constexpr int RCH   = 32;            // ref chunks (grid.y)
constexpr int CHUNK = N_ / RCH;      // 256 refs = 8 reg-resident A-frags
constexpr int NF    = CHUNK / 32;    // 8 fragments per wave
constexpr int RB    = 128;           // reduce blocks

#define FOLD(d, ma, mb)                                         \
    _Pragma("unroll")                                           \
    for (int r = 0; r < 8; r += 2)                              \
        ma = fminf(fminf(d[r], d[r + 1]), ma);                  \
    _Pragma("unroll")                                           \
    for (int r = 8; r < 16; r += 2)                             \
        mb = fminf(fminf(d[r], d[r + 1]), mb);

// prep: build A/B fragments + fp32 qsq for both clouds; zero out[0].
__global__ __launch_bounds__(TPB)
void prep_kernel(const float* __restrict__ src, const float* __restrict__ tgt,
                 f16x8* __restrict__ srcA, f16x8* __restrict__ srcB, float* __restrict__ srcS,
                 f16x8* __restrict__ tgtA, f16x8* __restrict__ tgtB, float* __restrict__ tgtS,
                 float* __restrict__ out)
{
    const _Float16 h0 = (_Float16)0.f;
    const _Float16 h1 = (_Float16)1.f;
    int t = blockIdx.x * TPB + threadIdx.x;
    {
        const float* p = src + (size_t)t * 3;
        _Float16 hx = (_Float16)p[0], hy = (_Float16)p[1], hz = (_Float16)p[2];
        float fx = (float)hx, fy = (float)hy, fz = (float)hz;
        float rsq = fx * fx + fy * fy + fz * fz;
        _Float16 rh = (_Float16)rsq;
        _Float16 rl = (_Float16)(rsq - (float)rh);
        srcA[t] = f16x8{(_Float16)(-2.f * fx), (_Float16)(-2.f * fy),
                        (_Float16)(-2.f * fz), rh, rl, h0, h0, h0};
        srcB[t] = f16x8{hx, hy, hz, h1, h1, h0, h0, h0};
        srcS[t] = rsq;
    }
    {
        const float* p = tgt + (size_t)t * 3;
        _Float16 hx = (_Float16)p[0], hy = (_Float16)p[1], hz = (_Float16)p[2];
        float fx = (float)hx, fy = (float)hy, fz = (float)hz;
        float rsq = fx * fx + fy * fy + fz * fz;
        _Float16 rh = (_Float16)rsq;
        _Float16 rl = (_Float16)(rsq - (float)rh);
        tgtA[t] = f16x8{(_Float16)(-2.f * fx), (_Float16)(-2.f * fy),
                        (_Float16)(-2.f * fz), rh, rl, h0, h0, h0};
        tgtB[t] = f16x8{hx, hy, hz, h1, h1, h0, h0, h0};
        tgtS[t] = rsq;
    }
    if (t == 0) out[0] = 0.f;
}

// grid: (N/QPB=32, RCH=32, 2*B=8) = 8192 blocks. No LDS, no barriers.
// part layout: part[(zb*RCH + c)*N + q]  (zb = dir*4+b), 8 MB total.
__global__ __launch_bounds__(TPB, 4)
void nn_reg_kernel(const f16x8* __restrict__ srcA, const f16x8* __restrict__ srcB,
                   const float* __restrict__ srcS,
                   const f16x8* __restrict__ tgtA, const f16x8* __restrict__ tgtB,
                   const float* __restrict__ tgtS,
                   float* __restrict__ part)
{
    const int zb  = blockIdx.z;
    const int dir = zb >> 2;            // 0: src queries tgt, 1: tgt queries src
    const int b   = zb & 3;
    const f16x8* Ap = (dir ? srcA : tgtA) + (size_t)b * N_ + (size_t)blockIdx.y * CHUNK;
    const f16x8* Bp = (dir ? tgtB : srcB) + (size_t)b * N_;
    const float* Sp = (dir ? tgtS : srcS) + (size_t)b * N_;
    float* opart = part + ((size_t)zb * RCH + blockIdx.y) * N_;

    const int tid  = threadIdx.x;
    const int lane = tid & 63;
    const int wv   = tid >> 6;
    const int l31  = lane & 31;
    const int half = lane >> 5;          // 0: carries data (k=0..7), 1: zeros
    const int qb   = blockIdx.x * QPB + wv * QPW;

    const _Float16 h0 = (_Float16)0.f;
    const f16x8 zf = {h0, h0, h0, h0, h0, h0, h0, h0};

    // register-resident fragments; upper lane-half keeps zeros (k=8..15)
    f16x8 B0 = zf, B1 = zf;
    float qs0 = 0.f, qs1 = 0.f;
    f16x8 A[NF];
#pragma unroll
    for (int u = 0; u < NF; ++u) A[u] = zf;
    if (half == 0) {
        B0  = Bp[qb + l31];
        B1  = Bp[qb + 32 + l31];
        qs0 = Sp[qb + l31];
        qs1 = Sp[qb + 32 + l31];
#pragma unroll
        for (int u = 0; u < NF; ++u) A[u] = Ap[u * 32 + l31];   // coalesced x4
    }

    const f32x16 zc = {};
    float mn0a = 3.0e38f, mn0b = 3.0e38f, mn1a = 3.0e38f, mn1b = 3.0e38f;

    // pure MFMA+fold loop, fully unrolled; ping-pong folds frag u-1's D
    // while frag u's MFMAs are in flight. Peak live D: 3 tiles (48 regs).
    f32x16 dA0 = __builtin_amdgcn_mfma_f32_32x32x16_f16(A[0], B0, zc, 0, 0, 0);
    f32x16 dA1 = __builtin_amdgcn_mfma_f32_32x32x16_f16(A[0], B1, zc, 0, 0, 0);
#pragma unroll
    for (int u = 1; u < NF; ++u) {
        f32x16 dB0 = __builtin_amdgcn_mfma_f32_32x32x16_f16(A[u], B0, zc, 0, 0, 0);
        FOLD(dA0, mn0a, mn0b)
        f32x16 dB1 = __builtin_amdgcn_mfma_f32_32x32x16_f16(A[u], B1, zc, 0, 0, 0);
        FOLD(dA1, mn1a, mn1b)
        dA0 = dB0;                       // renamed away by full unroll
        dA1 = dB1;
    }
    FOLD(dA0, mn0a, mn0b)
    FOLD(dA1, mn1a, mn1b)

    float mn0 = fminf(mn0a, mn0b);
    float mn1 = fminf(mn1a, mn1b);
    // rows split across lane halves: one xor-32 merge covers all 32 refs/tile
    mn0 = fminf(mn0, __shfl_xor(mn0, 32));
    mn1 = fminf(mn1, __shfl_xor(mn1, 32));
    if (half == 0) {
        opart[qb + l31]      = fmaxf(mn0 + qs0, 0.f);   // plain store, no init
        opart[qb + 32 + l31] = fmaxf(mn1 + qs1, 0.f);
    }
}

// reduce: per query min over RCH partials -> sqrt -> weight -> sum ->
// atomicAdd into out[0] (zeroed by prep). 8 MB of partials.
__global__ __launch_bounds__(TPB)
void reduce_kernel(const float* __restrict__ part,
                   const float* __restrict__ w,
                   float* __restrict__ out)
{
    const int Q = 2 * B_ * N_;               // 65536 queries
    const float invBN = 1.0f / (float)(B_ * N_);

    float sum = 0.0f;
    for (int t = blockIdx.x * TPB + threadIdx.x; t < Q; t += RB * TPB) {
        const int zb = t >> 13;              // t / N_
        const int qn = t & (N_ - 1);
        const float* p = part + ((size_t)zb * RCH) * N_ + qn;
        float m = p[0];
#pragma unroll
        for (int c = 1; c < RCH; ++c) m = fminf(m, p[(size_t)c * N_]);
        float d = sqrtf(m + EPS);
        sum += (zb < 4) ? d * w[(size_t)zb * N_ + qn] : d;
    }
    sum *= invBN;

    __shared__ float ss[TPB / 64];
    int lane = threadIdx.x & 63;
    int wid  = threadIdx.x >> 6;
#pragma unroll
    for (int off = 32; off > 0; off >>= 1) sum += __shfl_down(sum, off);
    if (lane == 0) ss[wid] = sum;
    __syncthreads();
    if (threadIdx.x == 0) {
        float s = 0.0f;
#pragma unroll
        for (int i = 0; i < TPB / 64; ++i) s += ss[i];
        atomicAdd(out, s);
    }
}

extern "C" void kernel_launch(void* const* d_in, const int* in_sizes, int n_in,
                              void* d_out, int out_size, void* d_ws, size_t ws_size,
                              hipStream_t stream)
{
    const float* src = (const float*)d_in[0];   // (B, N, 3)
    const float* tgt = (const float*)d_in[1];   // (B, M, 3)
    const float* w   = (const float*)d_in[2];   // (B, N)
    float* out = (float*)d_out;

    const size_t BN = (size_t)B_ * N_;
    char* p = (char*)d_ws;
    f16x8* srcA = (f16x8*)p;            p += BN * sizeof(f16x8);   // 512 KB
    f16x8* srcB = (f16x8*)p;            p += BN * sizeof(f16x8);
    f16x8* tgtA = (f16x8*)p;            p += BN * sizeof(f16x8);
    f16x8* tgtB = (f16x8*)p;            p += BN * sizeof(f16x8);
    float* srcS = (float*)p;            p += BN * sizeof(float);
    float* tgtS = (float*)p;            p += BN * sizeof(float);
    float* part = (float*)p;            // [2*B][RCH][N] = 8 MB, fully written

    prep_kernel<<<BN / TPB, TPB, 0, stream>>>(src, tgt, srcA, srcB, srcS,
                                              tgtA, tgtB, tgtS, out);

    dim3 grid(N_ / QPB, RCH, 2 * B_);   // 32 x 32 x 8 = 8192 blocks
    nn_reg_kernel<<<grid, TPB, 0, stream>>>(srcA, srcB, srcS,
                                            tgtA, tgtB, tgtS, part);

    reduce_kernel<<<RB, TPB, 0, stream>>>(part, w, out);
}